// Round 1
// baseline (2468.070 us; speedup 1.0000x reference)
//
#include <hip/hip_runtime.h>
#include <cstdint>
#include <cstddef>

#define SLOPE 0.2f
#define EPSV 1e-10f

__device__ __forceinline__ unsigned enc_f(float f) {
  unsigned u = __float_as_uint(f);
  return (u & 0x80000000u) ? ~u : (u | 0x80000000u);
}
__device__ __forceinline__ float dec_f(unsigned u) {
  return __uint_as_float((u & 0x80000000u) ? (u & 0x7FFFFFFFu) : ~u);
}

#define DOT4(F, Q) ((F).x*(Q).x + (F).y*(Q).y + (F).z*(Q).z + (F).w*(Q).w)

// K0: Qe[h][k] = sum_t (q[h][2t]+q[h][2t+1]) * We[16h+t][k];  cb[h] = sum_t (...) * be[16h+t]
__global__ void prep_qe(const float* __restrict__ We, const float* __restrict__ be,
                        const float* __restrict__ query, float* __restrict__ Qe,
                        float* __restrict__ cb) {
  int tid = threadIdx.x;  // 64 threads
  int h = tid >> 4, k = tid & 15;
  float acc = 0.f;
  for (int t = 0; t < 16; ++t) {
    float qs = query[h*32 + 2*t] + query[h*32 + 2*t + 1];
    acc += qs * We[(16*h + t)*16 + k];
  }
  Qe[h*16 + k] = acc;
  if (k == 0) {
    float accb = 0.f;
    for (int t = 0; t < 16; ++t) {
      float qs = query[h*32 + 2*t] + query[h*32 + 2*t + 1];
      accb += qs * be[16*h + t];
    }
    cb[h] = accb;
  }
}

// K1: hidden = x @ W^T + b  (N x 64), fused A[n,h]=sum qa*hidden, B[n,h]=sum qb*hidden
// block 256 = 64 cols x 4 thread-rows; each thread does 4 rows (register reuse of W).
__global__ __launch_bounds__(256) void hidden_ab(
    const float* __restrict__ x, const float* __restrict__ W,
    const float* __restrict__ b, const float* __restrict__ query,
    float* __restrict__ hidden, float* __restrict__ Av, float* __restrict__ Bv, int N) {
  int c = threadIdx.x & 63;
  int tr = threadIdx.x >> 6;
  int r0 = blockIdx.x * 16 + tr * 4;   // N % 4 == 0 assumed (N=100000)
  if (r0 >= N) return;
  const float4* w4 = (const float4*)(W + c * 128);
  const float4* x0 = (const float4*)(x + (size_t)(r0 + 0) * 128);
  const float4* x1 = (const float4*)(x + (size_t)(r0 + 1) * 128);
  const float4* x2 = (const float4*)(x + (size_t)(r0 + 2) * 128);
  const float4* x3 = (const float4*)(x + (size_t)(r0 + 3) * 128);
  float acc0 = 0.f, acc1 = 0.f, acc2 = 0.f, acc3 = 0.f;
#pragma unroll 4
  for (int k = 0; k < 32; ++k) {
    float4 w = w4[k];
    float4 a0 = x0[k]; acc0 += DOT4(a0, w);
    float4 a1 = x1[k]; acc1 += DOT4(a1, w);
    float4 a2 = x2[k]; acc2 += DOT4(a2, w);
    float4 a3 = x3[k]; acc3 += DOT4(a3, w);
  }
  float bc = b[c];
  acc0 += bc; acc1 += bc; acc2 += bc; acc3 += bc;
  hidden[(size_t)(r0 + 0) * 64 + c] = acc0;
  hidden[(size_t)(r0 + 1) * 64 + c] = acc1;
  hidden[(size_t)(r0 + 2) * 64 + c] = acc2;
  hidden[(size_t)(r0 + 3) * 64 + c] = acc3;
  // A/B reduction over the 16 lanes of each head
  int h = c >> 4, t = c & 15;
  float qa = query[h*32 + 2*t], qb = query[h*32 + 2*t + 1];
  float pa0 = qa*acc0, pa1 = qa*acc1, pa2 = qa*acc2, pa3 = qa*acc3;
  float pb0 = qb*acc0, pb1 = qb*acc1, pb2 = qb*acc2, pb3 = qb*acc3;
#pragma unroll
  for (int mask = 1; mask < 16; mask <<= 1) {
    pa0 += __shfl_xor(pa0, mask); pa1 += __shfl_xor(pa1, mask);
    pa2 += __shfl_xor(pa2, mask); pa3 += __shfl_xor(pa3, mask);
    pb0 += __shfl_xor(pb0, mask); pb1 += __shfl_xor(pb1, mask);
    pb2 += __shfl_xor(pb2, mask); pb3 += __shfl_xor(pb3, mask);
  }
  if (t == 0) {
    Av[(size_t)(r0 + 0)*4 + h] = pa0; Bv[(size_t)(r0 + 0)*4 + h] = pb0;
    Av[(size_t)(r0 + 1)*4 + h] = pa1; Bv[(size_t)(r0 + 1)*4 + h] = pb1;
    Av[(size_t)(r0 + 2)*4 + h] = pa2; Bv[(size_t)(r0 + 2)*4 + h] = pb2;
    Av[(size_t)(r0 + 3)*4 + h] = pa3; Bv[(size_t)(r0 + 3)*4 + h] = pb3;
  }
}

// K2: per-edge logits w[m,h] (leaky-relu'd), atomicMax into wmax, counts.
__global__ __launch_bounds__(256) void edge_w(
    const int* __restrict__ el, const float* __restrict__ ef,
    const float* __restrict__ Av, const float* __restrict__ Bv,
    const float* __restrict__ Qe, const float* __restrict__ cb,
    float* __restrict__ w_buf, unsigned* __restrict__ wmax,
    float* __restrict__ counts, int E, int M) {
  int m = blockIdx.x * 256 + threadIdx.x;
  if (m >= M) return;
  int nin, nout;
  if (m < E) { int2 e2 = ((const int2*)el)[m]; nin = e2.x; nout = e2.y; }
  else { nin = nout = m - E; }
  float4 a  = ((const float4*)Av)[nin];
  float4 bb = ((const float4*)Bv)[nout];
  float w0 = a.x + bb.x, w1 = a.y + bb.y, w2 = a.z + bb.z, w3 = a.w + bb.w;
  if (m < E) {
    const float4* ef4 = (const float4*)(ef + (size_t)m * 16);
    float4 f0 = ef4[0], f1 = ef4[1], f2 = ef4[2], f3 = ef4[3];
    const float4* q4 = (const float4*)Qe;
    float4 q;
    q = q4[0];  w0 += DOT4(f0, q);  q = q4[1];  w0 += DOT4(f1, q);
    q = q4[2];  w0 += DOT4(f2, q);  q = q4[3];  w0 += DOT4(f3, q);
    q = q4[4];  w1 += DOT4(f0, q);  q = q4[5];  w1 += DOT4(f1, q);
    q = q4[6];  w1 += DOT4(f2, q);  q = q4[7];  w1 += DOT4(f3, q);
    q = q4[8];  w2 += DOT4(f0, q);  q = q4[9];  w2 += DOT4(f1, q);
    q = q4[10]; w2 += DOT4(f2, q);  q = q4[11]; w2 += DOT4(f3, q);
    q = q4[12]; w3 += DOT4(f0, q);  q = q4[13]; w3 += DOT4(f1, q);
    q = q4[14]; w3 += DOT4(f2, q);  q = q4[15]; w3 += DOT4(f3, q);
    w0 += cb[0]; w1 += cb[1]; w2 += cb[2]; w3 += cb[3];
  }
  w0 = w0 > 0.f ? w0 : SLOPE * w0;
  w1 = w1 > 0.f ? w1 : SLOPE * w1;
  w2 = w2 > 0.f ? w2 : SLOPE * w2;
  w3 = w3 > 0.f ? w3 : SLOPE * w3;
  ((float4*)w_buf)[m] = make_float4(w0, w1, w2, w3);
  unsigned* wp = wmax + 4 * (size_t)nout;
  atomicMax(wp + 0, enc_f(w0));
  atomicMax(wp + 1, enc_f(w1));
  atomicMax(wp + 2, enc_f(w2));
  atomicMax(wp + 3, enc_f(w3));
  unsafeAtomicAdd(counts + nout, 1.0f);
}

// K3: att_un = exp(w - wmax[nout]) * ew; atomicAdd into norm (segment sums).
__global__ __launch_bounds__(256) void norm_pass(
    const int* __restrict__ el, const float* __restrict__ ew_arr,
    const float* __restrict__ w_buf, const unsigned* __restrict__ wmax,
    float* __restrict__ norm, int E, int M) {
  int m = blockIdx.x * 256 + threadIdx.x;
  if (m >= M) return;
  int nout; float ew;
  if (m < E) { nout = el[2*m + 1]; ew = ew_arr[m]; }
  else { nout = m - E; ew = 1.f; }
  float4 w = ((const float4*)w_buf)[m];
  uint4 u = ((const uint4*)wmax)[nout];
  float a0 = __expf(w.x - dec_f(u.x)) * ew;
  float a1 = __expf(w.y - dec_f(u.y)) * ew;
  float a2 = __expf(w.z - dec_f(u.z)) * ew;
  float a3 = __expf(w.w - dec_f(u.w)) * ew;
  float* np = norm + 4 * (size_t)nout;
  unsafeAtomicAdd(np + 0, a0);
  unsafeAtomicAdd(np + 1, a1);
  unsafeAtomicAdd(np + 2, a2);
  unsafeAtomicAdd(np + 3, a3);
}

// K5: per-node combined factor F = 1 / ((norm_sum/cnt + EPS) * cnt)
__global__ void f_pass(const float* __restrict__ norm, const float* __restrict__ counts,
                       float* __restrict__ F, int N) {
  int n = blockIdx.x * 256 + threadIdx.x;
  if (n >= N) return;
  float c = counts[n];
  float4 s = ((const float4*)norm)[n];
  float4 f;
  f.x = 1.f / ((s.x / c + EPSV) * c);
  f.y = 1.f / ((s.y / c + EPSV) * c);
  f.z = 1.f / ((s.z / c + EPSV) * c);
  f.w = 1.f / ((s.w / c + EPSV) * c);
  ((float4*)F)[n] = f;
}

// K4: scatter: out[nout,:] += exp(w-wmax)*ew*F * hidden[nin,:]  (16 lanes per edge)
__global__ __launch_bounds__(256) void scatter_out(
    const int* __restrict__ el, const float* __restrict__ ew_arr,
    const float* __restrict__ w_buf, const unsigned* __restrict__ wmax,
    const float* __restrict__ F, const float* __restrict__ hidden,
    float* __restrict__ out, int E, int M) {
  int t = blockIdx.x * 256 + threadIdx.x;
  int m = t >> 4;
  if (m >= M) return;
  int j = t & 15;
  int h = j >> 2;
  int nin, nout; float ew;
  if (m < E) { int2 e2 = ((const int2*)el)[m]; nin = e2.x; nout = e2.y; ew = ew_arr[m]; }
  else { nin = nout = m - E; ew = 1.f; }
  float w  = w_buf[4*(size_t)m + h];
  float wm = dec_f(wmax[4*(size_t)nout + h]);
  float s  = __expf(w - wm) * ew * F[4*(size_t)nout + h];
  float4 hv = *(const float4*)(hidden + (size_t)nin * 64 + 4*j);
  float* op = out + (size_t)nout * 64 + 4*j;
  unsafeAtomicAdd(op + 0, s * hv.x);
  unsafeAtomicAdd(op + 1, s * hv.y);
  unsafeAtomicAdd(op + 2, s * hv.z);
  unsafeAtomicAdd(op + 3, s * hv.w);
}

// K6: in-place relu
__global__ void relu_pass(float* __restrict__ out, int n) {
  int i = blockIdx.x * 256 + threadIdx.x;
  if (i >= n) return;
  float v = out[i];
  out[i] = v > 0.f ? v : 0.f;
}

extern "C" void kernel_launch(void* const* d_in, const int* in_sizes, int n_in,
                              void* d_out, int out_size, void* d_ws, size_t ws_size,
                              hipStream_t stream) {
  const int*   el = (const int*)d_in[0];
  const float* ew = (const float*)d_in[1];
  const float* ef = (const float*)d_in[2];
  const float* x  = (const float*)d_in[4];
  const float* W  = (const float*)d_in[5];
  const float* b  = (const float*)d_in[6];
  const float* We = (const float*)d_in[7];
  const float* be = (const float*)d_in[8];
  const float* q  = (const float*)d_in[9];
  int E = in_sizes[0] / 2;
  int N = in_sizes[4] / 128;
  int M = E + N;

  float* ws = (float*)d_ws;
  size_t off = 0;
  float* hidden = ws + off; off += (size_t)N * 64;
  float* w_buf  = ws + off; off += (size_t)M * 4;
  float* Av     = ws + off; off += (size_t)N * 4;
  float* Bv     = ws + off; off += (size_t)N * 4;
  float* normv  = ws + off; off += (size_t)N * 4;
  float* Fv     = ws + off; off += (size_t)N * 4;
  unsigned* wmaxv = (unsigned*)(ws + off); off += (size_t)N * 4;
  float* countsv  = ws + off; off += (size_t)N;
  float* Qe     = ws + off; off += 64;
  float* cb     = ws + off; off += 4;
  float* outp   = (float*)d_out;

  hipMemsetAsync(wmaxv, 0, (size_t)N * 4 * sizeof(unsigned), stream);
  hipMemsetAsync(countsv, 0, (size_t)N * sizeof(float), stream);
  hipMemsetAsync(normv, 0, (size_t)N * 4 * sizeof(float), stream);
  hipMemsetAsync(d_out, 0, (size_t)out_size * sizeof(float), stream);

  prep_qe<<<1, 64, 0, stream>>>(We, be, q, Qe, cb);
  hidden_ab<<<(N + 15) / 16, 256, 0, stream>>>(x, W, b, q, hidden, Av, Bv, N);
  edge_w<<<(M + 255) / 256, 256, 0, stream>>>(el, ef, Av, Bv, Qe, cb, w_buf, wmaxv, countsv, E, M);
  norm_pass<<<(M + 255) / 256, 256, 0, stream>>>(el, ew, w_buf, wmaxv, normv, E, M);
  f_pass<<<(N + 255) / 256, 256, 0, stream>>>(normv, countsv, Fv, N);
  scatter_out<<<(M * 16 + 255) / 256, 256, 0, stream>>>(el, ew, w_buf, wmaxv, Fv, hidden, outp, E, M);
  relu_pass<<<(N * 64 + 255) / 256, 256, 0, stream>>>(outp, N * 64);
}

// Round 3
// 874.847 us; speedup vs baseline: 2.8211x; 2.8211x over previous
//
#include <hip/hip_runtime.h>
#include <cstdint>
#include <cstddef>

#define SLOPE 0.2f
#define EPSV 1e-10f

__device__ __forceinline__ unsigned enc_f(float f) {
  unsigned u = __float_as_uint(f);
  return (u & 0x80000000u) ? ~u : (u | 0x80000000u);
}
__device__ __forceinline__ float dec_f(unsigned u) {
  return __uint_as_float((u & 0x80000000u) ? (u & 0x7FFFFFFFu) : ~u);
}

#define DOT4(F, Q) ((F).x*(Q).x + (F).y*(Q).y + (F).z*(Q).z + (F).w*(Q).w)

// K0: Qe[h][k] = sum_t (q[h][2t]+q[h][2t+1]) * We[16h+t][k];  cb[h] likewise with be
__global__ void prep_qe(const float* __restrict__ We, const float* __restrict__ be,
                        const float* __restrict__ query, float* __restrict__ Qe,
                        float* __restrict__ cb) {
  int tid = threadIdx.x;  // 64 threads
  int h = tid >> 4, k = tid & 15;
  float acc = 0.f;
  for (int t = 0; t < 16; ++t) {
    float qs = query[h*32 + 2*t] + query[h*32 + 2*t + 1];
    acc += qs * We[(16*h + t)*16 + k];
  }
  Qe[h*16 + k] = acc;
  if (k == 0) {
    float accb = 0.f;
    for (int t = 0; t < 16; ++t) {
      float qs = query[h*32 + 2*t] + query[h*32 + 2*t + 1];
      accb += qs * be[16*h + t];
    }
    cb[h] = accb;
  }
}

// K1: hidden = x @ W^T + b, fused A[n,h], B[n,h] head-projections.
__global__ __launch_bounds__(256) void hidden_ab(
    const float* __restrict__ x, const float* __restrict__ W,
    const float* __restrict__ b, const float* __restrict__ query,
    float* __restrict__ hidden, float* __restrict__ Av, float* __restrict__ Bv, int N) {
  int c = threadIdx.x & 63;
  int tr = threadIdx.x >> 6;
  int r0 = blockIdx.x * 16 + tr * 4;
  if (r0 >= N) return;
  const float4* w4 = (const float4*)(W + c * 128);
  const float4* x0 = (const float4*)(x + (size_t)(r0 + 0) * 128);
  const float4* x1 = (const float4*)(x + (size_t)(r0 + 1) * 128);
  const float4* x2 = (const float4*)(x + (size_t)(r0 + 2) * 128);
  const float4* x3 = (const float4*)(x + (size_t)(r0 + 3) * 128);
  float acc0 = 0.f, acc1 = 0.f, acc2 = 0.f, acc3 = 0.f;
#pragma unroll 4
  for (int k = 0; k < 32; ++k) {
    float4 w = w4[k];
    float4 a0 = x0[k]; acc0 += DOT4(a0, w);
    float4 a1 = x1[k]; acc1 += DOT4(a1, w);
    float4 a2 = x2[k]; acc2 += DOT4(a2, w);
    float4 a3 = x3[k]; acc3 += DOT4(a3, w);
  }
  float bc = b[c];
  acc0 += bc; acc1 += bc; acc2 += bc; acc3 += bc;
  hidden[(size_t)(r0 + 0) * 64 + c] = acc0;
  hidden[(size_t)(r0 + 1) * 64 + c] = acc1;
  hidden[(size_t)(r0 + 2) * 64 + c] = acc2;
  hidden[(size_t)(r0 + 3) * 64 + c] = acc3;
  int h = c >> 4, t = c & 15;
  float qa = query[h*32 + 2*t], qb = query[h*32 + 2*t + 1];
  float pa0 = qa*acc0, pa1 = qa*acc1, pa2 = qa*acc2, pa3 = qa*acc3;
  float pb0 = qb*acc0, pb1 = qb*acc1, pb2 = qb*acc2, pb3 = qb*acc3;
#pragma unroll
  for (int mask = 1; mask < 16; mask <<= 1) {
    pa0 += __shfl_xor(pa0, mask); pa1 += __shfl_xor(pa1, mask);
    pa2 += __shfl_xor(pa2, mask); pa3 += __shfl_xor(pa3, mask);
    pb0 += __shfl_xor(pb0, mask); pb1 += __shfl_xor(pb1, mask);
    pb2 += __shfl_xor(pb2, mask); pb3 += __shfl_xor(pb3, mask);
  }
  if (t == 0) {
    Av[(size_t)(r0 + 0)*4 + h] = pa0; Bv[(size_t)(r0 + 0)*4 + h] = pb0;
    Av[(size_t)(r0 + 1)*4 + h] = pa1; Bv[(size_t)(r0 + 1)*4 + h] = pb1;
    Av[(size_t)(r0 + 2)*4 + h] = pa2; Bv[(size_t)(r0 + 2)*4 + h] = pb2;
    Av[(size_t)(r0 + 3)*4 + h] = pa3; Bv[(size_t)(r0 + 3)*4 + h] = pb3;
  }
}

// K2: in-degree counts (including self-loops).
__global__ __launch_bounds__(256) void count_deg(
    const int* __restrict__ el, unsigned* __restrict__ counts, int E, int M) {
  int m = blockIdx.x * 256 + threadIdx.x;
  if (m >= M) return;
  int nout = (m < E) ? el[2*m + 1] : (m - E);
  atomicAdd(counts + nout, 1u);
}

// ---- 3-phase exclusive scan of counts[N] -> row_ptr[N+1], cursor[N] ----
#define SCAN_CHUNK 2048

__global__ __launch_bounds__(256) void scan_reduce(
    const unsigned* __restrict__ counts, unsigned* __restrict__ partial, int N) {
  __shared__ unsigned ssum[256];
  int t = threadIdx.x;
  int base = blockIdx.x * SCAN_CHUNK + t * 8;
  unsigned local = 0;
#pragma unroll
  for (int k = 0; k < 8; ++k) {
    int i = base + k;
    local += (i < N) ? counts[i] : 0u;
  }
  ssum[t] = local; __syncthreads();
  for (int off = 128; off > 0; off >>= 1) {
    if (t < off) ssum[t] += ssum[t + off];
    __syncthreads();
  }
  if (t == 0) partial[blockIdx.x] = ssum[0];
}

__global__ void scan_partials(unsigned* __restrict__ partial, int nb) {
  if (threadIdx.x == 0) {
    unsigned run = 0;
    for (int i = 0; i < nb; ++i) { unsigned v = partial[i]; partial[i] = run; run += v; }
  }
}

__global__ __launch_bounds__(256) void scan_scatter(
    const unsigned* __restrict__ counts, const unsigned* __restrict__ partial,
    unsigned* __restrict__ row_ptr, unsigned* __restrict__ cursor, int N, int M) {
  __shared__ unsigned ssum[256];
  int t = threadIdx.x;
  int base = blockIdx.x * SCAN_CHUNK + t * 8;
  unsigned v[8]; unsigned local = 0;
#pragma unroll
  for (int k = 0; k < 8; ++k) {
    int i = base + k;
    v[k] = (i < N) ? counts[i] : 0u;
    local += v[k];
  }
  ssum[t] = local; __syncthreads();
  for (int off = 1; off < 256; off <<= 1) {
    unsigned add = (t >= off) ? ssum[t - off] : 0u;
    __syncthreads();
    ssum[t] += add;
    __syncthreads();
  }
  unsigned run = partial[blockIdx.x] + (t ? ssum[t - 1] : 0u);
#pragma unroll
  for (int k = 0; k < 8; ++k) {
    int i = base + k;
    if (i < N) { row_ptr[i] = run; cursor[i] = run; run += v[k]; }
  }
  if (blockIdx.x == 0 && t == 0) row_ptr[N] = (unsigned)M;
}

// K3: per-edge logits (leaky-relu'd) + log(ew) folded in, written to CSR slot;
// wmax atomicMax.
__global__ __launch_bounds__(256) void edge_w(
    const int* __restrict__ el, const float* __restrict__ ef,
    const float* __restrict__ ew_arr,
    const float* __restrict__ Av, const float* __restrict__ Bv,
    const float* __restrict__ Qe, const float* __restrict__ cb,
    unsigned* __restrict__ wmax, unsigned* __restrict__ cursor,
    int* __restrict__ rec_nin, float4* __restrict__ rec_w, int E, int M) {
  int m = blockIdx.x * 256 + threadIdx.x;
  if (m >= M) return;
  int nin, nout;
  if (m < E) { int2 e2 = ((const int2*)el)[m]; nin = e2.x; nout = e2.y; }
  else { nin = nout = m - E; }
  float4 a  = ((const float4*)Av)[nin];
  float4 bb = ((const float4*)Bv)[nout];
  float w0 = a.x + bb.x, w1 = a.y + bb.y, w2 = a.z + bb.z, w3 = a.w + bb.w;
  float lew = 0.f;
  if (m < E) {
    const float4* ef4 = (const float4*)(ef + (size_t)m * 16);
    float4 f0 = ef4[0], f1 = ef4[1], f2 = ef4[2], f3 = ef4[3];
    const float4* q4 = (const float4*)Qe;
    float4 q;
    q = q4[0];  w0 += DOT4(f0, q);  q = q4[1];  w0 += DOT4(f1, q);
    q = q4[2];  w0 += DOT4(f2, q);  q = q4[3];  w0 += DOT4(f3, q);
    q = q4[4];  w1 += DOT4(f0, q);  q = q4[5];  w1 += DOT4(f1, q);
    q = q4[6];  w1 += DOT4(f2, q);  q = q4[7];  w1 += DOT4(f3, q);
    q = q4[8];  w2 += DOT4(f0, q);  q = q4[9];  w2 += DOT4(f1, q);
    q = q4[10]; w2 += DOT4(f2, q);  q = q4[11]; w2 += DOT4(f3, q);
    q = q4[12]; w3 += DOT4(f0, q);  q = q4[13]; w3 += DOT4(f1, q);
    q = q4[14]; w3 += DOT4(f2, q);  q = q4[15]; w3 += DOT4(f3, q);
    w0 += cb[0]; w1 += cb[1]; w2 += cb[2]; w3 += cb[3];
    lew = __logf(ew_arr[m]);
  }
  w0 = w0 > 0.f ? w0 : SLOPE * w0;
  w1 = w1 > 0.f ? w1 : SLOPE * w1;
  w2 = w2 > 0.f ? w2 : SLOPE * w2;
  w3 = w3 > 0.f ? w3 : SLOPE * w3;
  unsigned* wp = wmax + 4 * (size_t)nout;
  atomicMax(wp + 0, enc_f(w0));
  atomicMax(wp + 1, enc_f(w1));
  atomicMax(wp + 2, enc_f(w2));
  atomicMax(wp + 3, enc_f(w3));
  unsigned pos = atomicAdd(cursor + nout, 1u);
  rec_nin[pos] = nin;
  rec_w[pos] = make_float4(w0 + lew, w1 + lew, w2 + lew, w3 + lew);
}

// K4 (fused): per-node gather + online norm + F + relu. One wave per node.
__global__ __launch_bounds__(256) void gather_out(
    const unsigned* __restrict__ row_ptr, const int* __restrict__ rec_nin,
    const float4* __restrict__ rec_w, const unsigned* __restrict__ wmax,
    const float* __restrict__ hidden, float* __restrict__ out, int N) {
  int n = (blockIdx.x * 256 + threadIdx.x) >> 6;
  int lane = threadIdx.x & 63;
  if (n >= N) return;
  int h = lane >> 4;
  float wm = dec_f(wmax[4 * (size_t)n + h]);
  unsigned i0 = row_ptr[n], i1 = row_ptr[n + 1];
  float acc = 0.f, nsum = 0.f;
  int nin_cur = 0; float4 w_cur = make_float4(0,0,0,0);
  if (i0 < i1) { nin_cur = rec_nin[i0]; w_cur = rec_w[i0]; }
  for (unsigned i = i0; i < i1; ++i) {
    int nin_nxt = 0; float4 w_nxt = w_cur;
    if (i + 1 < i1) { nin_nxt = rec_nin[i + 1]; w_nxt = rec_w[i + 1]; }
    float hv = hidden[(size_t)nin_cur * 64 + lane];
    float wh = (h == 0) ? w_cur.x : (h == 1) ? w_cur.y : (h == 2) ? w_cur.z : w_cur.w;
    float a = __expf(wh - wm);
    nsum += a;
    acc += a * hv;
    nin_cur = nin_nxt; w_cur = w_nxt;
  }
  float c = (float)(i1 - i0);
  float F = 1.f / ((nsum / c + EPSV) * c);
  float v = acc * F;
  out[(size_t)n * 64 + lane] = v > 0.f ? v : 0.f;
}

extern "C" void kernel_launch(void* const* d_in, const int* in_sizes, int n_in,
                              void* d_out, int out_size, void* d_ws, size_t ws_size,
                              hipStream_t stream) {
  const int*   el = (const int*)d_in[0];
  const float* ew = (const float*)d_in[1];
  const float* ef = (const float*)d_in[2];
  const float* x  = (const float*)d_in[4];
  const float* W  = (const float*)d_in[5];
  const float* b  = (const float*)d_in[6];
  const float* We = (const float*)d_in[7];
  const float* be = (const float*)d_in[8];
  const float* q  = (const float*)d_in[9];
  int E = in_sizes[0] / 2;
  int N = in_sizes[4] / 128;
  int M = E + N;

  float* ws = (float*)d_ws;
  size_t off = 0;
  float* hidden = ws + off; off += (size_t)N * 64;
  float4* rec_w = (float4*)(ws + off); off += (size_t)M * 4;
  float* Av     = ws + off; off += (size_t)N * 4;
  float* Bv     = ws + off; off += (size_t)N * 4;
  unsigned* wmaxv  = (unsigned*)(ws + off); off += (size_t)N * 4;
  unsigned* row_ptr = (unsigned*)(ws + off); off += (size_t)N + 16;
  unsigned* counts  = (unsigned*)(ws + off); off += (size_t)N;
  unsigned* cursor  = (unsigned*)(ws + off); off += (size_t)N;
  unsigned* partial = (unsigned*)(ws + off); off += 64;
  int* rec_nin  = (int*)(ws + off); off += (size_t)M;
  float* Qe     = ws + off; off += 64;
  float* cb     = ws + off; off += 4;
  float* outp   = (float*)d_out;

  hipMemsetAsync(wmaxv, 0, (size_t)N * 4 * sizeof(unsigned), stream);
  hipMemsetAsync(counts, 0, (size_t)N * sizeof(unsigned), stream);

  int nb = (N + SCAN_CHUNK - 1) / SCAN_CHUNK;   // 49 for N=100k

  prep_qe<<<1, 64, 0, stream>>>(We, be, q, Qe, cb);
  hidden_ab<<<(N + 15) / 16, 256, 0, stream>>>(x, W, b, q, hidden, Av, Bv, N);
  count_deg<<<(M + 255) / 256, 256, 0, stream>>>(el, counts, E, M);
  scan_reduce<<<nb, 256, 0, stream>>>(counts, partial, N);
  scan_partials<<<1, 64, 0, stream>>>(partial, nb);
  scan_scatter<<<nb, 256, 0, stream>>>(counts, partial, row_ptr, cursor, N, M);
  edge_w<<<(M + 255) / 256, 256, 0, stream>>>(el, ef, ew, Av, Bv, Qe, cb,
                                              wmaxv, cursor, rec_nin, rec_w, E, M);
  gather_out<<<(N * 64 + 255) / 256, 256, 0, stream>>>(row_ptr, rec_nin, rec_w,
                                                       wmaxv, hidden, outp, N);
}

// Round 5
// 842.668 us; speedup vs baseline: 2.9289x; 1.0382x over previous
//
#include <hip/hip_runtime.h>
#include <cstdint>
#include <cstddef>

#define SLOPE 0.2f
#define EPSV 1e-10f

#define DOT4(F, Q) ((F).x*(Q).x + (F).y*(Q).y + (F).z*(Q).z + (F).w*(Q).w)

// K0: Qe[h][k] = sum_t (q[h][2t]+q[h][2t+1]) * We[16h+t][k];  cb[h] likewise with be
__global__ void prep_qe(const float* __restrict__ We, const float* __restrict__ be,
                        const float* __restrict__ query, float* __restrict__ Qe,
                        float* __restrict__ cb) {
  int tid = threadIdx.x;  // 64 threads
  int h = tid >> 4, k = tid & 15;
  float acc = 0.f;
  for (int t = 0; t < 16; ++t) {
    float qs = query[h*32 + 2*t] + query[h*32 + 2*t + 1];
    acc += qs * We[(16*h + t)*16 + k];
  }
  Qe[h*16 + k] = acc;
  if (k == 0) {
    float accb = 0.f;
    for (int t = 0; t < 16; ++t) {
      float qs = query[h*32 + 2*t] + query[h*32 + 2*t + 1];
      accb += qs * be[16*h + t];
    }
    cb[h] = accb;
  }
}

// K1: hidden = x @ W^T + b, fused A[n,h], B[n,h] head-projections.
__global__ __launch_bounds__(256) void hidden_ab(
    const float* __restrict__ x, const float* __restrict__ W,
    const float* __restrict__ b, const float* __restrict__ query,
    float* __restrict__ hidden, float* __restrict__ Av, float* __restrict__ Bv, int N) {
  int c = threadIdx.x & 63;
  int tr = threadIdx.x >> 6;
  int r0 = blockIdx.x * 16 + tr * 4;
  if (r0 >= N) return;
  const float4* w4 = (const float4*)(W + c * 128);
  const float4* x0 = (const float4*)(x + (size_t)(r0 + 0) * 128);
  const float4* x1 = (const float4*)(x + (size_t)(r0 + 1) * 128);
  const float4* x2 = (const float4*)(x + (size_t)(r0 + 2) * 128);
  const float4* x3 = (const float4*)(x + (size_t)(r0 + 3) * 128);
  float acc0 = 0.f, acc1 = 0.f, acc2 = 0.f, acc3 = 0.f;
#pragma unroll 4
  for (int k = 0; k < 32; ++k) {
    float4 w = w4[k];
    float4 a0 = x0[k]; acc0 += DOT4(a0, w);
    float4 a1 = x1[k]; acc1 += DOT4(a1, w);
    float4 a2 = x2[k]; acc2 += DOT4(a2, w);
    float4 a3 = x3[k]; acc3 += DOT4(a3, w);
  }
  float bc = b[c];
  acc0 += bc; acc1 += bc; acc2 += bc; acc3 += bc;
  hidden[(size_t)(r0 + 0) * 64 + c] = acc0;
  hidden[(size_t)(r0 + 1) * 64 + c] = acc1;
  hidden[(size_t)(r0 + 2) * 64 + c] = acc2;
  hidden[(size_t)(r0 + 3) * 64 + c] = acc3;
  int h = c >> 4, t = c & 15;
  float qa = query[h*32 + 2*t], qb = query[h*32 + 2*t + 1];
  float pa0 = qa*acc0, pa1 = qa*acc1, pa2 = qa*acc2, pa3 = qa*acc3;
  float pb0 = qb*acc0, pb1 = qb*acc1, pb2 = qb*acc2, pb3 = qb*acc3;
#pragma unroll
  for (int mask = 1; mask < 16; mask <<= 1) {
    pa0 += __shfl_xor(pa0, mask); pa1 += __shfl_xor(pa1, mask);
    pa2 += __shfl_xor(pa2, mask); pa3 += __shfl_xor(pa3, mask);
    pb0 += __shfl_xor(pb0, mask); pb1 += __shfl_xor(pb1, mask);
    pb2 += __shfl_xor(pb2, mask); pb3 += __shfl_xor(pb3, mask);
  }
  if (t == 0) {
    Av[(size_t)(r0 + 0)*4 + h] = pa0; Bv[(size_t)(r0 + 0)*4 + h] = pb0;
    Av[(size_t)(r0 + 1)*4 + h] = pa1; Bv[(size_t)(r0 + 1)*4 + h] = pb1;
    Av[(size_t)(r0 + 2)*4 + h] = pa2; Bv[(size_t)(r0 + 2)*4 + h] = pb2;
    Av[(size_t)(r0 + 3)*4 + h] = pa3; Bv[(size_t)(r0 + 3)*4 + h] = pb3;
  }
}

// K2: in-degree counts over real edges only (self-loop added in scan as +1).
__global__ __launch_bounds__(256) void count_deg(
    const int* __restrict__ el, unsigned* __restrict__ counts, int E) {
  int m = blockIdx.x * 256 + threadIdx.x;
  if (m >= E) return;
  int2 e2 = ((const int2*)el)[m];
  atomicAdd(counts + e2.y, 1u);
}

// ---- 3-phase exclusive scan of (counts[i]+1) -> row_ptr[N+1], cursor[N] ----
// Slot row_ptr[n] is reserved for the implicit self-loop (never written);
// cursor starts at row_ptr[n]+1.
#define SCAN_CHUNK 2048

__global__ __launch_bounds__(256) void scan_reduce(
    const unsigned* __restrict__ counts, unsigned* __restrict__ partial, int N) {
  __shared__ unsigned ssum[256];
  int t = threadIdx.x;
  int base = blockIdx.x * SCAN_CHUNK + t * 8;
  unsigned local = 0;
#pragma unroll
  for (int k = 0; k < 8; ++k) {
    int i = base + k;
    local += (i < N) ? (counts[i] + 1u) : 0u;
  }
  ssum[t] = local; __syncthreads();
  for (int off = 128; off > 0; off >>= 1) {
    if (t < off) ssum[t] += ssum[t + off];
    __syncthreads();
  }
  if (t == 0) partial[blockIdx.x] = ssum[0];
}

__global__ void scan_partials(unsigned* __restrict__ partial, int nb) {
  if (threadIdx.x == 0) {
    unsigned run = 0;
    for (int i = 0; i < nb; ++i) { unsigned v = partial[i]; partial[i] = run; run += v; }
  }
}

__global__ __launch_bounds__(256) void scan_scatter(
    const unsigned* __restrict__ counts, const unsigned* __restrict__ partial,
    unsigned* __restrict__ row_ptr, unsigned* __restrict__ cursor, int N, int M) {
  __shared__ unsigned ssum[256];
  int t = threadIdx.x;
  int base = blockIdx.x * SCAN_CHUNK + t * 8;
  unsigned v[8]; unsigned local = 0;
#pragma unroll
  for (int k = 0; k < 8; ++k) {
    int i = base + k;
    v[k] = (i < N) ? (counts[i] + 1u) : 0u;
    local += v[k];
  }
  ssum[t] = local; __syncthreads();
  for (int off = 1; off < 256; off <<= 1) {
    unsigned add = (t >= off) ? ssum[t - off] : 0u;
    __syncthreads();
    ssum[t] += add;
    __syncthreads();
  }
  unsigned run = partial[blockIdx.x] + (t ? ssum[t - 1] : 0u);
#pragma unroll
  for (int k = 0; k < 8; ++k) {
    int i = base + k;
    if (i < N) { row_ptr[i] = run; cursor[i] = run + 1u; run += v[k]; }
  }
  if (blockIdx.x == 0 && t == 0) row_ptr[N] = (unsigned)M;
}

// K3: scatter edge index into CSR slot (4B per edge; only scattered op left).
__global__ __launch_bounds__(256) void scatter_idx(
    const int* __restrict__ el, unsigned* __restrict__ cursor,
    unsigned* __restrict__ csr_idx, int E) {
  int m = blockIdx.x * 256 + threadIdx.x;
  if (m >= E) return;
  int2 e2 = ((const int2*)el)[m];
  unsigned pos = atomicAdd(cursor + e2.y, 1u);
  csr_idx[pos] = (unsigned)m;
}

// K4 (mega-fused): per-node wave recomputes logits from ef + Av/Bv/Qe/cb,
// online softmax-mean (no max shift: cancels algebraically, eps term ~1e-8 rel),
// accumulates hidden gather, relu, single coalesced store.
// lane l = h*16+k holds Qe[l]; 4x shfl_xor reduces the 16-dot.
__global__ __launch_bounds__(256) void gather_mega(
    const unsigned* __restrict__ row_ptr, const unsigned* __restrict__ csr_idx,
    const int* __restrict__ el, const float* __restrict__ ew_arr,
    const float* __restrict__ ef,
    const float* __restrict__ Av, const float* __restrict__ Bv,
    const float* __restrict__ Qe, const float* __restrict__ cb,
    const float* __restrict__ hidden, float* __restrict__ out, int N) {
  int n = (blockIdx.x * 256 + threadIdx.x) >> 6;
  int lane = threadIdx.x & 63;
  if (n >= N) return;
  int h = lane >> 4, k = lane & 15;
  float qe  = Qe[lane];
  float cbh = cb[h];
  float bh  = Bv[4 * (size_t)n + h];
  // implicit self-loop: w = A[n,h] + B[n,h]  (zero edge-feature row, ew=1)
  float wself = Av[4 * (size_t)n + h] + bh;
  wself = wself > 0.f ? wself : SLOPE * wself;
  float a = __expf(wself);
  float nsum = a;
  float acc = a * hidden[(size_t)n * 64 + lane];

  unsigned i0 = row_ptr[n], i1 = row_ptr[n + 1];
  unsigned i = i0 + 1;
  // 2-stage pipeline: edge-data loads for i+1 issued while computing i.
  int m_cur = 0, nin_cur = 0; float ew_cur = 0.f, ef_cur = 0.f;
  if (i < i1) {
    m_cur = (int)csr_idx[i];
    nin_cur = el[2 * m_cur];
    ew_cur  = ew_arr[m_cur];
    ef_cur  = ef[(size_t)m_cur * 16 + k];
  }
  for (; i < i1; ++i) {
    int m_nxt = 0, nin_nxt = 0; float ew_nxt = 0.f, ef_nxt = 0.f;
    if (i + 1 < i1) {
      m_nxt = (int)csr_idx[i + 1];
      nin_nxt = el[2 * m_nxt];
      ew_nxt  = ew_arr[m_nxt];
      ef_nxt  = ef[(size_t)m_nxt * 16 + k];
    }
    float hv = hidden[(size_t)nin_cur * 64 + lane];
    float av = Av[4 * (size_t)nin_cur + h];
    float p = ef_cur * qe;
    p += __shfl_xor(p, 1);
    p += __shfl_xor(p, 2);
    p += __shfl_xor(p, 4);
    p += __shfl_xor(p, 8);
    float w = p + av + bh + cbh;
    w = w > 0.f ? w : SLOPE * w;
    float aa = __expf(w) * ew_cur;
    nsum += aa;
    acc  += aa * hv;
    m_cur = m_nxt; nin_cur = nin_nxt; ew_cur = ew_nxt; ef_cur = ef_nxt;
  }
  float c = (float)(i1 - i0);
  float F = 1.f / ((nsum / c + EPSV) * c);
  float v = acc * F;
  out[(size_t)n * 64 + lane] = v > 0.f ? v : 0.f;
}

extern "C" void kernel_launch(void* const* d_in, const int* in_sizes, int n_in,
                              void* d_out, int out_size, void* d_ws, size_t ws_size,
                              hipStream_t stream) {
  const int*   el = (const int*)d_in[0];
  const float* ew = (const float*)d_in[1];
  const float* ef = (const float*)d_in[2];
  const float* x  = (const float*)d_in[4];
  const float* W  = (const float*)d_in[5];
  const float* b  = (const float*)d_in[6];
  const float* We = (const float*)d_in[7];
  const float* be = (const float*)d_in[8];
  const float* q  = (const float*)d_in[9];
  int E = in_sizes[0] / 2;
  int N = in_sizes[4] / 128;
  int M = E + N;

  float* ws = (float*)d_ws;
  size_t off = 0;
  float* hidden = ws + off; off += (size_t)N * 64;
  float* Av     = ws + off; off += (size_t)N * 4;
  float* Bv     = ws + off; off += (size_t)N * 4;
  unsigned* counts  = (unsigned*)(ws + off); off += (size_t)N;
  unsigned* row_ptr = (unsigned*)(ws + off); off += (size_t)N + 16;
  unsigned* cursor  = (unsigned*)(ws + off); off += (size_t)N;
  unsigned* csr_idx = (unsigned*)(ws + off); off += (size_t)M + 16;
  unsigned* partial = (unsigned*)(ws + off); off += 64;
  float* Qe     = ws + off; off += 64;
  float* cb     = ws + off; off += 4;
  float* outp   = (float*)d_out;

  hipMemsetAsync(counts, 0, (size_t)N * sizeof(unsigned), stream);

  int nb = (N + SCAN_CHUNK - 1) / SCAN_CHUNK;   // 49 for N=100k

  prep_qe<<<1, 64, 0, stream>>>(We, be, q, Qe, cb);
  hidden_ab<<<(N + 15) / 16, 256, 0, stream>>>(x, W, b, q, hidden, Av, Bv, N);
  count_deg<<<(E + 255) / 256, 256, 0, stream>>>(el, counts, E);
  scan_reduce<<<nb, 256, 0, stream>>>(counts, partial, N);
  scan_partials<<<1, 64, 0, stream>>>(partial, nb);
  scan_scatter<<<nb, 256, 0, stream>>>(counts, partial, row_ptr, cursor, N, M);
  scatter_idx<<<(E + 255) / 256, 256, 0, stream>>>(el, cursor, csr_idx, E);
  gather_mega<<<(N * 64 + 255) / 256, 256, 0, stream>>>(
      row_ptr, csr_idx, el, ew, ef, Av, Bv, Qe, cb, hidden, outp, N);
}

// Round 6
// 625.575 us; speedup vs baseline: 3.9453x; 1.3470x over previous
//
#include <hip/hip_runtime.h>
#include <hip/hip_fp16.h>
#include <cstdint>
#include <cstddef>

#define SLOPE 0.2f
#define EPSV 1e-10f
#define NPART 8

#define DOT4(F, Q) ((F).x*(Q).x + (F).y*(Q).y + (F).z*(Q).z + (F).w*(Q).w)

__device__ __forceinline__ float h2_as_float(__half2 v) {
  union { __half2 h; float f; } u; u.h = v; return u.f;
}
__device__ __forceinline__ __half2 float_as_h2(float v) {
  union { float f; __half2 h; } u; u.f = v; return u.h;
}

// K0: Qe[h][k] = sum_t (q[h][2t]+q[h][2t+1]) * We[16h+t][k];  cb[h] likewise with be
__global__ void prep_qe(const float* __restrict__ We, const float* __restrict__ be,
                        const float* __restrict__ query, float* __restrict__ Qe,
                        float* __restrict__ cb) {
  int tid = threadIdx.x;  // 64 threads
  int h = tid >> 4, k = tid & 15;
  float acc = 0.f;
  for (int t = 0; t < 16; ++t) {
    float qs = query[h*32 + 2*t] + query[h*32 + 2*t + 1];
    acc += qs * We[(16*h + t)*16 + k];
  }
  Qe[h*16 + k] = acc;
  if (k == 0) {
    float accb = 0.f;
    for (int t = 0; t < 16; ++t) {
      float qs = query[h*32 + 2*t] + query[h*32 + 2*t + 1];
      accb += qs * be[16*h + t];
    }
    cb[h] = accb;
  }
}

// K1: hidden = x @ W^T + b, fused A[n,h], B[n,h] head-projections.
__global__ __launch_bounds__(256) void hidden_ab(
    const float* __restrict__ x, const float* __restrict__ W,
    const float* __restrict__ b, const float* __restrict__ query,
    float* __restrict__ hidden, float* __restrict__ Av, float* __restrict__ Bv, int N) {
  int c = threadIdx.x & 63;
  int tr = threadIdx.x >> 6;
  int r0 = blockIdx.x * 16 + tr * 4;
  if (r0 >= N) return;
  const float4* w4 = (const float4*)(W + c * 128);
  const float4* x0 = (const float4*)(x + (size_t)(r0 + 0) * 128);
  const float4* x1 = (const float4*)(x + (size_t)(r0 + 1) * 128);
  const float4* x2 = (const float4*)(x + (size_t)(r0 + 2) * 128);
  const float4* x3 = (const float4*)(x + (size_t)(r0 + 3) * 128);
  float acc0 = 0.f, acc1 = 0.f, acc2 = 0.f, acc3 = 0.f;
#pragma unroll 4
  for (int k = 0; k < 32; ++k) {
    float4 w = w4[k];
    float4 a0 = x0[k]; acc0 += DOT4(a0, w);
    float4 a1 = x1[k]; acc1 += DOT4(a1, w);
    float4 a2 = x2[k]; acc2 += DOT4(a2, w);
    float4 a3 = x3[k]; acc3 += DOT4(a3, w);
  }
  float bc = b[c];
  acc0 += bc; acc1 += bc; acc2 += bc; acc3 += bc;
  hidden[(size_t)(r0 + 0) * 64 + c] = acc0;
  hidden[(size_t)(r0 + 1) * 64 + c] = acc1;
  hidden[(size_t)(r0 + 2) * 64 + c] = acc2;
  hidden[(size_t)(r0 + 3) * 64 + c] = acc3;
  int h = c >> 4, t = c & 15;
  float qa = query[h*32 + 2*t], qb = query[h*32 + 2*t + 1];
  float pa0 = qa*acc0, pa1 = qa*acc1, pa2 = qa*acc2, pa3 = qa*acc3;
  float pb0 = qb*acc0, pb1 = qb*acc1, pb2 = qb*acc2, pb3 = qb*acc3;
#pragma unroll
  for (int mask = 1; mask < 16; mask <<= 1) {
    pa0 += __shfl_xor(pa0, mask); pa1 += __shfl_xor(pa1, mask);
    pa2 += __shfl_xor(pa2, mask); pa3 += __shfl_xor(pa3, mask);
    pb0 += __shfl_xor(pb0, mask); pb1 += __shfl_xor(pb1, mask);
    pb2 += __shfl_xor(pb2, mask); pb3 += __shfl_xor(pb3, mask);
  }
  if (t == 0) {
    Av[(size_t)(r0 + 0)*4 + h] = pa0; Bv[(size_t)(r0 + 0)*4 + h] = pb0;
    Av[(size_t)(r0 + 1)*4 + h] = pa1; Bv[(size_t)(r0 + 1)*4 + h] = pb1;
    Av[(size_t)(r0 + 2)*4 + h] = pa2; Bv[(size_t)(r0 + 2)*4 + h] = pb2;
    Av[(size_t)(r0 + 3)*4 + h] = pa3; Bv[(size_t)(r0 + 3)*4 + h] = pb3;
  }
}

// K2: 8-way partitioned in-degree histogram. Partition = blockIdx.x & 7.
// MUST use the same grid/block shape as edge_rec so edge m maps to the same
// partition in both passes.
__global__ __launch_bounds__(256) void count_deg8(
    const int* __restrict__ el, unsigned* __restrict__ counts8, int E, int N) {
  int m = blockIdx.x * 256 + threadIdx.x;
  if (m >= E) return;
  int2 e2 = ((const int2*)el)[m];
  atomicAdd(counts8 + (size_t)(blockIdx.x & (NPART - 1)) * N + e2.y, 1u);
}

// ---- scan of per-node totals -> row_ptr[N+1] and 8 per-partition cursors ----
#define SCAN_CHUNK 2048

__global__ __launch_bounds__(256) void scan_reduce(
    const unsigned* __restrict__ counts8, unsigned* __restrict__ partial, int N) {
  __shared__ unsigned ssum[256];
  int t = threadIdx.x;
  int base = blockIdx.x * SCAN_CHUNK + t * 8;
  unsigned local = 0;
#pragma unroll
  for (int k = 0; k < 8; ++k) {
    int i = base + k;
    if (i < N) {
      unsigned tot = 0;
#pragma unroll
      for (int p = 0; p < NPART; ++p) tot += counts8[(size_t)p * N + i];
      local += tot;
    }
  }
  ssum[t] = local; __syncthreads();
  for (int off = 128; off > 0; off >>= 1) {
    if (t < off) ssum[t] += ssum[t + off];
    __syncthreads();
  }
  if (t == 0) partial[blockIdx.x] = ssum[0];
}

__global__ void scan_partials(unsigned* __restrict__ partial, int nb) {
  if (threadIdx.x == 0) {
    unsigned run = 0;
    for (int i = 0; i < nb; ++i) { unsigned v = partial[i]; partial[i] = run; run += v; }
  }
}

__global__ __launch_bounds__(256) void scan_scatter(
    const unsigned* __restrict__ counts8, const unsigned* __restrict__ partial,
    unsigned* __restrict__ row_ptr, unsigned* __restrict__ cursor8, int N, int E) {
  __shared__ unsigned ssum[256];
  int t = threadIdx.x;
  int base = blockIdx.x * SCAN_CHUNK + t * 8;
  unsigned tot[8]; unsigned local = 0;
#pragma unroll
  for (int k = 0; k < 8; ++k) {
    int i = base + k;
    unsigned s = 0;
    if (i < N) {
#pragma unroll
      for (int p = 0; p < NPART; ++p) s += counts8[(size_t)p * N + i];
    }
    tot[k] = s; local += s;
  }
  ssum[t] = local; __syncthreads();
  for (int off = 1; off < 256; off <<= 1) {
    unsigned add = (t >= off) ? ssum[t - off] : 0u;
    __syncthreads();
    ssum[t] += add;
    __syncthreads();
  }
  unsigned run = partial[blockIdx.x] + (t ? ssum[t - 1] : 0u);
#pragma unroll
  for (int k = 0; k < 8; ++k) {
    int i = base + k;
    if (i < N) {
      row_ptr[i] = run;
      unsigned pref = run;
#pragma unroll
      for (int p = 0; p < NPART; ++p) {
        cursor8[(size_t)p * N + i] = pref;
        pref += counts8[(size_t)p * N + i];
      }
      run += tot[k];
    }
  }
  if (blockIdx.x == 0 && t == 0) row_ptr[N] = (unsigned)E;
}

// K3: edge-parallel attention-weight records. Per edge: logits from streamed ef
// + L2-resident Av/Bv gathers, aa_h = exp(leaky(w))*ew as fp16x4, one aligned
// 16B scattered store {nin, aa01, aa23, 0} into the CSR slot claimed from the
// partitioned cursor.
__global__ __launch_bounds__(256) void edge_rec(
    const int* __restrict__ el, const float* __restrict__ ew_arr,
    const float* __restrict__ ef,
    const float* __restrict__ Av, const float* __restrict__ Bv,
    const float* __restrict__ Qe, const float* __restrict__ cb,
    unsigned* __restrict__ cursor8, float4* __restrict__ rec, int E, int N) {
  int m = blockIdx.x * 256 + threadIdx.x;
  if (m >= E) return;
  int2 e2 = ((const int2*)el)[m];
  const float4* ef4 = (const float4*)(ef + (size_t)m * 16);
  float4 f0 = ef4[0], f1 = ef4[1], f2 = ef4[2], f3 = ef4[3];
  const float4* q4 = (const float4*)Qe;
  float w0, w1, w2, w3;
  {
    float4 q;
    q = q4[0];  w0  = DOT4(f0, q);  q = q4[1];  w0 += DOT4(f1, q);
    q = q4[2];  w0 += DOT4(f2, q);  q = q4[3];  w0 += DOT4(f3, q);
    q = q4[4];  w1  = DOT4(f0, q);  q = q4[5];  w1 += DOT4(f1, q);
    q = q4[6];  w1 += DOT4(f2, q);  q = q4[7];  w1 += DOT4(f3, q);
    q = q4[8];  w2  = DOT4(f0, q);  q = q4[9];  w2 += DOT4(f1, q);
    q = q4[10]; w2 += DOT4(f2, q);  q = q4[11]; w2 += DOT4(f3, q);
    q = q4[12]; w3  = DOT4(f0, q);  q = q4[13]; w3 += DOT4(f1, q);
    q = q4[14]; w3 += DOT4(f2, q);  q = q4[15]; w3 += DOT4(f3, q);
  }
  float4 av = ((const float4*)Av)[e2.x];
  float4 bv = ((const float4*)Bv)[e2.y];
  w0 += av.x + bv.x + cb[0];
  w1 += av.y + bv.y + cb[1];
  w2 += av.z + bv.z + cb[2];
  w3 += av.w + bv.w + cb[3];
  w0 = w0 > 0.f ? w0 : SLOPE * w0;
  w1 = w1 > 0.f ? w1 : SLOPE * w1;
  w2 = w2 > 0.f ? w2 : SLOPE * w2;
  w3 = w3 > 0.f ? w3 : SLOPE * w3;
  float ew = ew_arr[m];
  float a0 = __expf(w0) * ew, a1 = __expf(w1) * ew;
  float a2 = __expf(w2) * ew, a3 = __expf(w3) * ew;
  unsigned pos = atomicAdd(cursor8 + (size_t)(blockIdx.x & (NPART - 1)) * N + e2.y, 1u);
  float4 r;
  r.x = __int_as_float(e2.x);
  r.y = h2_as_float(__floats2half2_rn(a0, a1));
  r.z = h2_as_float(__floats2half2_rn(a2, a3));
  r.w = 0.f;
  rec[pos] = r;
}

// K4: per-node gather, 4 edges per wave iteration, float4 hidden loads.
// lane = g*16 + j; group g handles edges base+g; lane j covers features 4j..4j+3
// (all in head h = j>>2). Self-loop handled by group 0. Butterfly over masks
// {16,32} sums groups; group 0 stores the row.
__global__ __launch_bounds__(256) void gather_rec(
    const unsigned* __restrict__ row_ptr, const float4* __restrict__ rec,
    const float* __restrict__ Av, const float* __restrict__ Bv,
    const float* __restrict__ hidden, float* __restrict__ out, int N) {
  int n = (blockIdx.x * 256 + threadIdx.x) >> 6;
  if (n >= N) return;
  int lane = threadIdx.x & 63;
  int g = lane >> 4, j = lane & 15, h = j >> 2;
  unsigned i0 = row_ptr[n], i1 = row_ptr[n + 1];
  float4 acc = make_float4(0.f, 0.f, 0.f, 0.f);
  float nsum = 0.f;

  // self-loop: aa = exp(leaky(A[n,h]+B[n,h])), group 0 only
  if (g == 0) {
    float4 av = ((const float4*)Av)[n];
    float4 bv = ((const float4*)Bv)[n];
    float avh = (h == 0) ? av.x : (h == 1) ? av.y : (h == 2) ? av.z : av.w;
    float bvh = (h == 0) ? bv.x : (h == 1) ? bv.y : (h == 2) ? bv.z : bv.w;
    float w = avh + bvh;
    w = w > 0.f ? w : SLOPE * w;
    float aas = __expf(w);
    nsum = aas;
    float4 hv = *(const float4*)(hidden + (size_t)n * 64 + 4 * j);
    acc.x = aas * hv.x; acc.y = aas * hv.y; acc.z = aas * hv.z; acc.w = aas * hv.w;
  }

  // 2-stage pipelined 4-edge loop
  unsigned idx = i0 + g;
  float4 r_cur = (idx < i1) ? rec[idx] : make_float4(0.f, 0.f, 0.f, 0.f);
  for (unsigned base = i0; base < i1; base += 4) {
    unsigned nidx = base + 4 + g;
    float4 r_nxt = (nidx < i1) ? rec[nidx] : make_float4(0.f, 0.f, 0.f, 0.f);
    int nin = __float_as_int(r_cur.x);
    __half2 aa01 = float_as_h2(r_cur.y);
    __half2 aa23 = float_as_h2(r_cur.z);
    float aa = (h == 0) ? __low2float(aa01) : (h == 1) ? __high2float(aa01)
             : (h == 2) ? __low2float(aa23) : __high2float(aa23);
    float4 hv = *(const float4*)(hidden + (size_t)nin * 64 + 4 * j);
    nsum += aa;
    acc.x += aa * hv.x; acc.y += aa * hv.y; acc.z += aa * hv.z; acc.w += aa * hv.w;
    r_cur = r_nxt;
  }

  // reduce across the 4 groups (lanes j, j+16, j+32, j+48)
#pragma unroll
  for (int mask = 16; mask <= 32; mask <<= 1) {
    acc.x += __shfl_xor(acc.x, mask);
    acc.y += __shfl_xor(acc.y, mask);
    acc.z += __shfl_xor(acc.z, mask);
    acc.w += __shfl_xor(acc.w, mask);
    nsum  += __shfl_xor(nsum, mask);
  }
  if (g == 0) {
    float c = (float)(i1 - i0 + 1u);
    float F = 1.f / ((nsum / c + EPSV) * c);
    float4 v;
    v.x = acc.x * F; v.y = acc.y * F; v.z = acc.z * F; v.w = acc.w * F;
    v.x = v.x > 0.f ? v.x : 0.f;
    v.y = v.y > 0.f ? v.y : 0.f;
    v.z = v.z > 0.f ? v.z : 0.f;
    v.w = v.w > 0.f ? v.w : 0.f;
    *(float4*)(out + (size_t)n * 64 + 4 * j) = v;
  }
}

extern "C" void kernel_launch(void* const* d_in, const int* in_sizes, int n_in,
                              void* d_out, int out_size, void* d_ws, size_t ws_size,
                              hipStream_t stream) {
  const int*   el = (const int*)d_in[0];
  const float* ew = (const float*)d_in[1];
  const float* ef = (const float*)d_in[2];
  const float* x  = (const float*)d_in[4];
  const float* W  = (const float*)d_in[5];
  const float* b  = (const float*)d_in[6];
  const float* We = (const float*)d_in[7];
  const float* be = (const float*)d_in[8];
  const float* q  = (const float*)d_in[9];
  int E = in_sizes[0] / 2;
  int N = in_sizes[4] / 128;

  float* ws = (float*)d_ws;
  size_t off = 0;
  float* hidden = ws + off; off += (size_t)N * 64;
  float4* rec   = (float4*)(ws + off); off += (size_t)E * 4 + 16;
  float* Av     = ws + off; off += (size_t)N * 4;
  float* Bv     = ws + off; off += (size_t)N * 4;
  unsigned* counts8 = (unsigned*)(ws + off); off += (size_t)N * NPART;
  unsigned* cursor8 = (unsigned*)(ws + off); off += (size_t)N * NPART;
  unsigned* row_ptr = (unsigned*)(ws + off); off += (size_t)N + 16;
  unsigned* partial = (unsigned*)(ws + off); off += 64;
  float* Qe     = ws + off; off += 64;
  float* cb     = ws + off; off += 4;
  float* outp   = (float*)d_out;

  hipMemsetAsync(counts8, 0, (size_t)N * NPART * sizeof(unsigned), stream);

  int nb = (N + SCAN_CHUNK - 1) / SCAN_CHUNK;   // 49 for N=100k
  int eb = (E + 255) / 256;

  prep_qe<<<1, 64, 0, stream>>>(We, be, q, Qe, cb);
  hidden_ab<<<(N + 15) / 16, 256, 0, stream>>>(x, W, b, q, hidden, Av, Bv, N);
  count_deg8<<<eb, 256, 0, stream>>>(el, counts8, E, N);
  scan_reduce<<<nb, 256, 0, stream>>>(counts8, partial, N);
  scan_partials<<<1, 64, 0, stream>>>(partial, nb);
  scan_scatter<<<nb, 256, 0, stream>>>(counts8, partial, row_ptr, cursor8, N, E);
  edge_rec<<<eb, 256, 0, stream>>>(el, ew, ef, Av, Bv, Qe, cb, cursor8, rec, E, N);
  gather_rec<<<(N * 64 + 255) / 256, 256, 0, stream>>>(row_ptr, rec, Av, Bv,
                                                       hidden, outp, N);
}

// Round 7
// 568.331 us; speedup vs baseline: 4.3427x; 1.1007x over previous
//
#include <hip/hip_runtime.h>
#include <hip/hip_fp16.h>
#include <cstdint>
#include <cstddef>

#define SLOPE 0.2f
#define EPSV 1e-10f
#define NPART 8

#define DOT4(F, Q) ((F).x*(Q).x + (F).y*(Q).y + (F).z*(Q).z + (F).w*(Q).w)

__device__ __forceinline__ float h2_as_float(__half2 v) {
  union { __half2 h; float f; } u; u.h = v; return u.f;
}
__device__ __forceinline__ __half2 float_as_h2(float v) {
  union { float f; __half2 h; } u; u.f = v; return u.h;
}

// K0: Qe[h][k] = sum_t (q[h][2t]+q[h][2t+1]) * We[16h+t][k];  cb[h] likewise with be
__global__ void prep_qe(const float* __restrict__ We, const float* __restrict__ be,
                        const float* __restrict__ query, float* __restrict__ Qe,
                        float* __restrict__ cb) {
  int tid = threadIdx.x;  // 64 threads
  int h = tid >> 4, k = tid & 15;
  float acc = 0.f;
  for (int t = 0; t < 16; ++t) {
    float qs = query[h*32 + 2*t] + query[h*32 + 2*t + 1];
    acc += qs * We[(16*h + t)*16 + k];
  }
  Qe[h*16 + k] = acc;
  if (k == 0) {
    float accb = 0.f;
    for (int t = 0; t < 16; ++t) {
      float qs = query[h*32 + 2*t] + query[h*32 + 2*t + 1];
      accb += qs * be[16*h + t];
    }
    cb[h] = accb;
  }
}

// K1: hidden = x @ W^T + b, fused A[n,h], B[n,h] head-projections.
// W staged per-block into LDS transposed with pad-65: WT[k*65+c].
// Compute-side LDS banks: (65k+c)%32 = (k+c)%32 -> 2-way (free).
// Staging-side: lane t writes addr t*65+2i -> (t+2i)%32 -> 2-way (free).
// x loads are wave-uniform float4 broadcasts (1 line/instr).
__global__ __launch_bounds__(256) void hidden_ab(
    const float* __restrict__ x, const float* __restrict__ W,
    const float* __restrict__ b, const float* __restrict__ query,
    float* __restrict__ hidden, float* __restrict__ Av, float* __restrict__ Bv, int N) {
  __shared__ float WT[128 * 65];
  int t = threadIdx.x;
#pragma unroll
  for (int i = 0; i < 32; ++i) {
    int idx = t + 256 * i;            // 0..8191 over flat W[c*128+k]
    int cc = idx >> 7, kk = idx & 127;
    WT[kk * 65 + cc] = W[idx];
  }
  __syncthreads();

  int c = t & 63;
  int tr = t >> 6;
  int r0 = blockIdx.x * 16 + tr * 4;
  if (r0 >= N) return;
  const float4* x0 = (const float4*)(x + (size_t)(r0 + 0) * 128);
  const float4* x1 = (const float4*)(x + (size_t)(r0 + 1) * 128);
  const float4* x2 = (const float4*)(x + (size_t)(r0 + 2) * 128);
  const float4* x3 = (const float4*)(x + (size_t)(r0 + 3) * 128);
  float acc0 = 0.f, acc1 = 0.f, acc2 = 0.f, acc3 = 0.f;
#pragma unroll 4
  for (int kk = 0; kk < 128; kk += 4) {
    float4 a0 = x0[kk >> 2];
    float4 a1 = x1[kk >> 2];
    float4 a2 = x2[kk >> 2];
    float4 a3 = x3[kk >> 2];
    float w0 = WT[(kk + 0) * 65 + c];
    float w1 = WT[(kk + 1) * 65 + c];
    float w2 = WT[(kk + 2) * 65 + c];
    float w3 = WT[(kk + 3) * 65 + c];
    acc0 += a0.x * w0 + a0.y * w1 + a0.z * w2 + a0.w * w3;
    acc1 += a1.x * w0 + a1.y * w1 + a1.z * w2 + a1.w * w3;
    acc2 += a2.x * w0 + a2.y * w1 + a2.z * w2 + a2.w * w3;
    acc3 += a3.x * w0 + a3.y * w1 + a3.z * w2 + a3.w * w3;
  }
  float bc = b[c];
  acc0 += bc; acc1 += bc; acc2 += bc; acc3 += bc;
  hidden[(size_t)(r0 + 0) * 64 + c] = acc0;
  hidden[(size_t)(r0 + 1) * 64 + c] = acc1;
  hidden[(size_t)(r0 + 2) * 64 + c] = acc2;
  hidden[(size_t)(r0 + 3) * 64 + c] = acc3;
  int h = c >> 4, tt = c & 15;
  float qa = query[h*32 + 2*tt], qb = query[h*32 + 2*tt + 1];
  float pa0 = qa*acc0, pa1 = qa*acc1, pa2 = qa*acc2, pa3 = qa*acc3;
  float pb0 = qb*acc0, pb1 = qb*acc1, pb2 = qb*acc2, pb3 = qb*acc3;
#pragma unroll
  for (int mask = 1; mask < 16; mask <<= 1) {
    pa0 += __shfl_xor(pa0, mask); pa1 += __shfl_xor(pa1, mask);
    pa2 += __shfl_xor(pa2, mask); pa3 += __shfl_xor(pa3, mask);
    pb0 += __shfl_xor(pb0, mask); pb1 += __shfl_xor(pb1, mask);
    pb2 += __shfl_xor(pb2, mask); pb3 += __shfl_xor(pb3, mask);
  }
  if (tt == 0) {
    Av[(size_t)(r0 + 0)*4 + h] = pa0; Bv[(size_t)(r0 + 0)*4 + h] = pb0;
    Av[(size_t)(r0 + 1)*4 + h] = pa1; Bv[(size_t)(r0 + 1)*4 + h] = pb1;
    Av[(size_t)(r0 + 2)*4 + h] = pa2; Bv[(size_t)(r0 + 2)*4 + h] = pb2;
    Av[(size_t)(r0 + 3)*4 + h] = pa3; Bv[(size_t)(r0 + 3)*4 + h] = pb3;
  }
}

// K2: 8-way partitioned in-degree histogram. Partition = blockIdx.x & 7.
// MUST use the same grid/block shape as edge_rec so edge m maps to the same
// partition in both passes.
__global__ __launch_bounds__(256) void count_deg8(
    const int* __restrict__ el, unsigned* __restrict__ counts8, int E, int N) {
  int m = blockIdx.x * 256 + threadIdx.x;
  if (m >= E) return;
  int2 e2 = ((const int2*)el)[m];
  atomicAdd(counts8 + (size_t)(blockIdx.x & (NPART - 1)) * N + e2.y, 1u);
}

// ---- scan of per-node totals -> row_ptr[N+1] and 8 per-partition cursors ----
#define SCAN_CHUNK 2048

__global__ __launch_bounds__(256) void scan_reduce(
    const unsigned* __restrict__ counts8, unsigned* __restrict__ partial, int N) {
  __shared__ unsigned ssum[256];
  int t = threadIdx.x;
  int base = blockIdx.x * SCAN_CHUNK + t * 8;
  unsigned local = 0;
#pragma unroll
  for (int k = 0; k < 8; ++k) {
    int i = base + k;
    if (i < N) {
      unsigned tot = 0;
#pragma unroll
      for (int p = 0; p < NPART; ++p) tot += counts8[(size_t)p * N + i];
      local += tot;
    }
  }
  ssum[t] = local; __syncthreads();
  for (int off = 128; off > 0; off >>= 1) {
    if (t < off) ssum[t] += ssum[t + off];
    __syncthreads();
  }
  if (t == 0) partial[blockIdx.x] = ssum[0];
}

__global__ void scan_partials(unsigned* __restrict__ partial, int nb) {
  if (threadIdx.x == 0) {
    unsigned run = 0;
    for (int i = 0; i < nb; ++i) { unsigned v = partial[i]; partial[i] = run; run += v; }
  }
}

__global__ __launch_bounds__(256) void scan_scatter(
    const unsigned* __restrict__ counts8, const unsigned* __restrict__ partial,
    unsigned* __restrict__ row_ptr, unsigned* __restrict__ cursor8, int N, int E) {
  __shared__ unsigned ssum[256];
  int t = threadIdx.x;
  int base = blockIdx.x * SCAN_CHUNK + t * 8;
  unsigned tot[8]; unsigned local = 0;
#pragma unroll
  for (int k = 0; k < 8; ++k) {
    int i = base + k;
    unsigned s = 0;
    if (i < N) {
#pragma unroll
      for (int p = 0; p < NPART; ++p) s += counts8[(size_t)p * N + i];
    }
    tot[k] = s; local += s;
  }
  ssum[t] = local; __syncthreads();
  for (int off = 1; off < 256; off <<= 1) {
    unsigned add = (t >= off) ? ssum[t - off] : 0u;
    __syncthreads();
    ssum[t] += add;
    __syncthreads();
  }
  unsigned run = partial[blockIdx.x] + (t ? ssum[t - 1] : 0u);
#pragma unroll
  for (int k = 0; k < 8; ++k) {
    int i = base + k;
    if (i < N) {
      row_ptr[i] = run;
      unsigned pref = run;
#pragma unroll
      for (int p = 0; p < NPART; ++p) {
        cursor8[(size_t)p * N + i] = pref;
        pref += counts8[(size_t)p * N + i];
      }
      run += tot[k];
    }
  }
  if (blockIdx.x == 0 && t == 0) row_ptr[N] = (unsigned)E;
}

// K3: edge-parallel attention-weight records. Per edge: logits from streamed ef
// + L2-resident Av/Bv gathers, aa_h = exp(leaky(w))*ew as fp16x4, one aligned
// 16B scattered store {nin, aa01, aa23, 0} into the CSR slot claimed from the
// partitioned cursor.
__global__ __launch_bounds__(256) void edge_rec(
    const int* __restrict__ el, const float* __restrict__ ew_arr,
    const float* __restrict__ ef,
    const float* __restrict__ Av, const float* __restrict__ Bv,
    const float* __restrict__ Qe, const float* __restrict__ cb,
    unsigned* __restrict__ cursor8, float4* __restrict__ rec, int E, int N) {
  int m = blockIdx.x * 256 + threadIdx.x;
  if (m >= E) return;
  int2 e2 = ((const int2*)el)[m];
  const float4* ef4 = (const float4*)(ef + (size_t)m * 16);
  float4 f0 = ef4[0], f1 = ef4[1], f2 = ef4[2], f3 = ef4[3];
  const float4* q4 = (const float4*)Qe;
  float w0, w1, w2, w3;
  {
    float4 q;
    q = q4[0];  w0  = DOT4(f0, q);  q = q4[1];  w0 += DOT4(f1, q);
    q = q4[2];  w0 += DOT4(f2, q);  q = q4[3];  w0 += DOT4(f3, q);
    q = q4[4];  w1  = DOT4(f0, q);  q = q4[5];  w1 += DOT4(f1, q);
    q = q4[6];  w1 += DOT4(f2, q);  q = q4[7];  w1 += DOT4(f3, q);
    q = q4[8];  w2  = DOT4(f0, q);  q = q4[9];  w2 += DOT4(f1, q);
    q = q4[10]; w2 += DOT4(f2, q);  q = q4[11]; w2 += DOT4(f3, q);
    q = q4[12]; w3  = DOT4(f0, q);  q = q4[13]; w3 += DOT4(f1, q);
    q = q4[14]; w3 += DOT4(f2, q);  q = q4[15]; w3 += DOT4(f3, q);
  }
  float4 av = ((const float4*)Av)[e2.x];
  float4 bv = ((const float4*)Bv)[e2.y];
  w0 += av.x + bv.x + cb[0];
  w1 += av.y + bv.y + cb[1];
  w2 += av.z + bv.z + cb[2];
  w3 += av.w + bv.w + cb[3];
  w0 = w0 > 0.f ? w0 : SLOPE * w0;
  w1 = w1 > 0.f ? w1 : SLOPE * w1;
  w2 = w2 > 0.f ? w2 : SLOPE * w2;
  w3 = w3 > 0.f ? w3 : SLOPE * w3;
  float ew = ew_arr[m];
  float a0 = __expf(w0) * ew, a1 = __expf(w1) * ew;
  float a2 = __expf(w2) * ew, a3 = __expf(w3) * ew;
  unsigned pos = atomicAdd(cursor8 + (size_t)(blockIdx.x & (NPART - 1)) * N + e2.y, 1u);
  float4 r;
  r.x = __int_as_float(e2.x);
  r.y = h2_as_float(__floats2half2_rn(a0, a1));
  r.z = h2_as_float(__floats2half2_rn(a2, a3));
  r.w = 0.f;
  rec[pos] = r;
}

// K4: per-node gather, 4 edges per wave iteration, float4 hidden loads.
// lane = g*16 + j; group g handles edges base+g; lane j covers features 4j..4j+3
// (all in head h = j>>2). Self-loop handled by group 0. Butterfly over masks
// {16,32} sums groups; group 0 stores the row.
__global__ __launch_bounds__(256) void gather_rec(
    const unsigned* __restrict__ row_ptr, const float4* __restrict__ rec,
    const float* __restrict__ Av, const float* __restrict__ Bv,
    const float* __restrict__ hidden, float* __restrict__ out, int N) {
  int n = (blockIdx.x * 256 + threadIdx.x) >> 6;
  if (n >= N) return;
  int lane = threadIdx.x & 63;
  int g = lane >> 4, j = lane & 15, h = j >> 2;
  unsigned i0 = row_ptr[n], i1 = row_ptr[n + 1];
  float4 acc = make_float4(0.f, 0.f, 0.f, 0.f);
  float nsum = 0.f;

  // self-loop: aa = exp(leaky(A[n,h]+B[n,h])), group 0 only
  if (g == 0) {
    float4 av = ((const float4*)Av)[n];
    float4 bv = ((const float4*)Bv)[n];
    float avh = (h == 0) ? av.x : (h == 1) ? av.y : (h == 2) ? av.z : av.w;
    float bvh = (h == 0) ? bv.x : (h == 1) ? bv.y : (h == 2) ? bv.z : bv.w;
    float w = avh + bvh;
    w = w > 0.f ? w : SLOPE * w;
    float aas = __expf(w);
    nsum = aas;
    float4 hv = *(const float4*)(hidden + (size_t)n * 64 + 4 * j);
    acc.x = aas * hv.x; acc.y = aas * hv.y; acc.z = aas * hv.z; acc.w = aas * hv.w;
  }

  // 2-stage pipelined 4-edge loop
  unsigned idx = i0 + g;
  float4 r_cur = (idx < i1) ? rec[idx] : make_float4(0.f, 0.f, 0.f, 0.f);
  for (unsigned base = i0; base < i1; base += 4) {
    unsigned nidx = base + 4 + g;
    float4 r_nxt = (nidx < i1) ? rec[nidx] : make_float4(0.f, 0.f, 0.f, 0.f);
    int nin = __float_as_int(r_cur.x);
    __half2 aa01 = float_as_h2(r_cur.y);
    __half2 aa23 = float_as_h2(r_cur.z);
    float aa = (h == 0) ? __low2float(aa01) : (h == 1) ? __high2float(aa01)
             : (h == 2) ? __low2float(aa23) : __high2float(aa23);
    float4 hv = *(const float4*)(hidden + (size_t)nin * 64 + 4 * j);
    nsum += aa;
    acc.x += aa * hv.x; acc.y += aa * hv.y; acc.z += aa * hv.z; acc.w += aa * hv.w;
    r_cur = r_nxt;
  }

  // reduce across the 4 groups (lanes j, j+16, j+32, j+48)
#pragma unroll
  for (int mask = 16; mask <= 32; mask <<= 1) {
    acc.x += __shfl_xor(acc.x, mask);
    acc.y += __shfl_xor(acc.y, mask);
    acc.z += __shfl_xor(acc.z, mask);
    acc.w += __shfl_xor(acc.w, mask);
    nsum  += __shfl_xor(nsum, mask);
  }
  if (g == 0) {
    float c = (float)(i1 - i0 + 1u);
    float F = 1.f / ((nsum / c + EPSV) * c);
    float4 v;
    v.x = acc.x * F; v.y = acc.y * F; v.z = acc.z * F; v.w = acc.w * F;
    v.x = v.x > 0.f ? v.x : 0.f;
    v.y = v.y > 0.f ? v.y : 0.f;
    v.z = v.z > 0.f ? v.z : 0.f;
    v.w = v.w > 0.f ? v.w : 0.f;
    *(float4*)(out + (size_t)n * 64 + 4 * j) = v;
  }
}

extern "C" void kernel_launch(void* const* d_in, const int* in_sizes, int n_in,
                              void* d_out, int out_size, void* d_ws, size_t ws_size,
                              hipStream_t stream) {
  const int*   el = (const int*)d_in[0];
  const float* ew = (const float*)d_in[1];
  const float* ef = (const float*)d_in[2];
  const float* x  = (const float*)d_in[4];
  const float* W  = (const float*)d_in[5];
  const float* b  = (const float*)d_in[6];
  const float* We = (const float*)d_in[7];
  const float* be = (const float*)d_in[8];
  const float* q  = (const float*)d_in[9];
  int E = in_sizes[0] / 2;
  int N = in_sizes[4] / 128;

  float* ws = (float*)d_ws;
  size_t off = 0;
  float* hidden = ws + off; off += (size_t)N * 64;
  float4* rec   = (float4*)(ws + off); off += (size_t)E * 4 + 16;
  float* Av     = ws + off; off += (size_t)N * 4;
  float* Bv     = ws + off; off += (size_t)N * 4;
  unsigned* counts8 = (unsigned*)(ws + off); off += (size_t)N * NPART;
  unsigned* cursor8 = (unsigned*)(ws + off); off += (size_t)N * NPART;
  unsigned* row_ptr = (unsigned*)(ws + off); off += (size_t)N + 16;
  unsigned* partial = (unsigned*)(ws + off); off += 64;
  float* Qe     = ws + off; off += 64;
  float* cb     = ws + off; off += 4;
  float* outp   = (float*)d_out;

  hipMemsetAsync(counts8, 0, (size_t)N * NPART * sizeof(unsigned), stream);

  int nb = (N + SCAN_CHUNK - 1) / SCAN_CHUNK;   // 49 for N=100k
  int eb = (E + 255) / 256;

  prep_qe<<<1, 64, 0, stream>>>(We, be, q, Qe, cb);
  hidden_ab<<<(N + 15) / 16, 256, 0, stream>>>(x, W, b, q, hidden, Av, Bv, N);
  count_deg8<<<eb, 256, 0, stream>>>(el, counts8, E, N);
  scan_reduce<<<nb, 256, 0, stream>>>(counts8, partial, N);
  scan_partials<<<1, 64, 0, stream>>>(partial, nb);
  scan_scatter<<<nb, 256, 0, stream>>>(counts8, partial, row_ptr, cursor8, N, E);
  edge_rec<<<eb, 256, 0, stream>>>(el, ew, ef, Av, Bv, Qe, cb, cursor8, rec, E, N);
  gather_rec<<<(N * 64 + 255) / 256, 256, 0, stream>>>(row_ptr, rec, Av, Bv,
                                                       hidden, outp, N);
}